// Round 3
// baseline (438.751 us; speedup 1.0000x reference)
//
#include <hip/hip_runtime.h>

#define N_NODES 10000
#define N_EDGES 160000
#define FEAT 512
#define M_PAD 10048   // 157 * 64

typedef unsigned short ushort_t;
typedef unsigned int uint32;

typedef __attribute__((ext_vector_type(8))) short short8;       // 8 bf16 (4 VGPRs)
typedef __attribute__((ext_vector_type(8))) unsigned short ush8;
typedef __attribute__((ext_vector_type(4))) float f32x4;        // MFMA C/D

__device__ __forceinline__ ushort_t f2bf(float f) {
    uint32 u = __float_as_uint(f);
    u += 0x7FFF + ((u >> 16) & 1);   // round-to-nearest-even
    return (ushort_t)(u >> 16);
}
__device__ __forceinline__ float bf2f(ushort_t h) {
    return __uint_as_float(((uint32)h) << 16);
}

__device__ __forceinline__ void load_lds16(const ushort_t* g, ushort_t* l) {
    __builtin_amdgcn_global_load_lds(
        (const __attribute__((address_space(1))) void*)g,
        (__attribute__((address_space(3))) void*)l, 16, 0, 0);
}

__device__ __forceinline__ void fma4(float4& a, float w, const float4 v) {
    a.x += w * v.x; a.y += w * v.y; a.z += w * v.z; a.w += w * v.w;
}

// ---------------- degree count ----------------
__global__ void deg_kernel(const int* __restrict__ src, const int* __restrict__ dst,
                           int* __restrict__ deg_out, int* __restrict__ deg_in) {
    int e = blockIdx.x * blockDim.x + threadIdx.x;
    if (e < N_EDGES) {
        atomicAdd(&deg_out[src[e]], 1);
        atomicAdd(&deg_in[dst[e]], 1);
    }
}

// ---------------- norms ----------------
__global__ void norm_kernel(const int* __restrict__ deg_out, const int* __restrict__ deg_in,
                            float* __restrict__ norm_out, float* __restrict__ norm_in) {
    int i = blockIdx.x * blockDim.x + threadIdx.x;
    if (i < N_NODES) {
        int dob = deg_out[i], dib = deg_in[i];
        norm_out[i] = dob > 0 ? rsqrtf((float)dob) : 0.f;
        norm_in[i]  = dib > 0 ? rsqrtf((float)dib) : 0.f;
    }
}

// ---------------- exclusive scan of in-degrees ----------------
__global__ void scan_kernel(const int* __restrict__ deg_in,
                            int* __restrict__ row_ptr, int* __restrict__ cursor) {
    __shared__ int sums[256];
    const int CHUNK = 40;
    int t = threadIdx.x;
    int start = t * CHUNK;
    int s = 0;
    for (int j = 0; j < CHUNK; j++) {
        int i = start + j;
        if (i < N_NODES) s += deg_in[i];
    }
    sums[t] = s;
    __syncthreads();
    for (int off = 1; off < 256; off <<= 1) {
        int v = (t >= off) ? sums[t - off] : 0;
        __syncthreads();
        sums[t] += v;
        __syncthreads();
    }
    int run = (t > 0) ? sums[t - 1] : 0;
    for (int j = 0; j < CHUNK; j++) {
        int i = start + j;
        if (i < N_NODES) {
            row_ptr[i] = run;
            cursor[i] = run;
            run += deg_in[i];
        }
    }
    if (t == 0) row_ptr[N_NODES] = sums[255];
}

// ---------------- CSR fill ----------------
__global__ void fill_kernel(const int* __restrict__ src, const int* __restrict__ dst,
                            int* __restrict__ cursor, int* __restrict__ edge_src) {
    int e = blockIdx.x * blockDim.x + threadIdx.x;
    if (e < N_EDGES) {
        int d = dst[e];
        int pos = atomicAdd(&cursor[d], 1);
        edge_src[pos] = src[e];
    }
}

// ---------------- aggregation v2: one wave per dst, 4x edge unroll ----------------
// out[d] = norm_in[d] * sum norm_out[s]*x[s]; epilogue writes bf16 hi/lo split.
__global__ __launch_bounds__(256) void agg_kernel(const float* __restrict__ x,
        const int* __restrict__ edge_src, const int* __restrict__ row_ptr,
        const float* __restrict__ norm_out, const float* __restrict__ norm_in,
        ushort_t* __restrict__ a_hi, ushort_t* __restrict__ a_lo) {
    int lane = threadIdx.x & 63;
    int d = blockIdx.x * 4 + (threadIdx.x >> 6);   // 4 waves/block, one dst each
    float4 aa = make_float4(0.f, 0.f, 0.f, 0.f);
    float4 ab = make_float4(0.f, 0.f, 0.f, 0.f);
    if (d < N_NODES) {
        int beg = row_ptr[d], end = row_ptr[d + 1];
        const float4* xb = ((const float4*)x) + lane * 2;  // lane covers feats [lane*8, lane*8+8)
        int e = beg;
        for (; e + 4 <= end; e += 4) {
            int s0 = edge_src[e + 0], s1 = edge_src[e + 1];
            int s2 = edge_src[e + 2], s3 = edge_src[e + 3];
            float w0 = norm_out[s0], w1 = norm_out[s1];
            float w2 = norm_out[s2], w3 = norm_out[s3];
            float4 v0a = xb[s0 * 128], v0b = xb[s0 * 128 + 1];
            float4 v1a = xb[s1 * 128], v1b = xb[s1 * 128 + 1];
            float4 v2a = xb[s2 * 128], v2b = xb[s2 * 128 + 1];
            float4 v3a = xb[s3 * 128], v3b = xb[s3 * 128 + 1];
            fma4(aa, w0, v0a); fma4(ab, w0, v0b);
            fma4(aa, w1, v1a); fma4(ab, w1, v1b);
            fma4(aa, w2, v2a); fma4(ab, w2, v2b);
            fma4(aa, w3, v3a); fma4(ab, w3, v3b);
        }
        for (; e < end; e++) {
            int s = edge_src[e];
            float w = norm_out[s];
            fma4(aa, w, xb[s * 128]);
            fma4(ab, w, xb[s * 128 + 1]);
        }
        float ni = norm_in[d];
        aa.x *= ni; aa.y *= ni; aa.z *= ni; aa.w *= ni;
        ab.x *= ni; ab.y *= ni; ab.z *= ni; ab.w *= ni;
    }
    float vv[8] = {aa.x, aa.y, aa.z, aa.w, ab.x, ab.y, ab.z, ab.w};
    ush8 h8, l8;
#pragma unroll
    for (int i = 0; i < 8; i++) {
        ushort_t h = f2bf(vv[i]);
        h8[i] = h;
        l8[i] = f2bf(vv[i] - bf2f(h));
    }
    *(ush8*)&a_hi[(size_t)d * 512 + lane * 8] = h8;
    *(ush8*)&a_lo[(size_t)d * 512 + lane * 8] = l8;
}

// ---------------- W (KxN fp32) -> W^T hi/lo (NxK bf16), tiled transpose ----------------
__global__ __launch_bounds__(256) void wsplit_kernel(const float* __restrict__ W1,
        const float* __restrict__ W2, const float* __restrict__ W3,
        ushort_t* __restrict__ wt_hi, ushort_t* __restrict__ wt_lo) {
    __shared__ float tile[32][33];
    const float* W = blockIdx.z == 0 ? W1 : (blockIdx.z == 1 ? W2 : W3);
    ushort_t* th = wt_hi + (size_t)blockIdx.z * 512 * 512;
    ushort_t* tl = wt_lo + (size_t)blockIdx.z * 512 * 512;
    int tx = threadIdx.x, ty = threadIdx.y;   // block (32,8)
    int n0 = blockIdx.x * 32, k0 = blockIdx.y * 32;
#pragma unroll
    for (int i = 0; i < 4; i++)
        tile[ty + i * 8][tx] = W[(size_t)(k0 + ty + i * 8) * 512 + n0 + tx];
    __syncthreads();
#pragma unroll
    for (int i = 0; i < 4; i++) {
        float v = tile[tx][ty + i * 8];          // = W[k0+tx][n0+ty+i*8]
        int n = n0 + ty + i * 8, k = k0 + tx;
        ushort_t hb = f2bf(v);
        th[(size_t)n * 512 + k] = hb;
        tl[(size_t)n * 512 + k] = f2bf(v - bf2f(hb));
    }
}

// ---------------- split-bf16 MFMA GEMM, frag-interleaved LDS ----------------
// C = A(M_PAD x 512) @ W(512 x N) + bias.  BM=64, BN=128, BK=32; 4 waves,
// wave tile 32x64 (2x4 16x16 MFMA tiles, 3 split terms each).
// LDS layout: strip t = 16 rows; slot (t*64 + kg*16 + (r&15)) * 8 ushorts, so
// fragment reads are ds_read_b128 at base + lane*16B (conflict-free), and
// global_load_lds staging keeps its wave-uniform-base + lane*16B contract.
// Dual-output: columns >= 512 go to Cb with bias_b (block-uniform branch).
template <bool RELU_A, bool RELU_B>
__global__ __launch_bounds__(256) void mfma_gemm(
        const ushort_t* __restrict__ A_hi, const ushort_t* __restrict__ A_lo,
        const ushort_t* __restrict__ Bt_hi, const ushort_t* __restrict__ Bt_lo,
        const float* __restrict__ bias_a, const float* __restrict__ bias_b,
        float* __restrict__ Ca, float* __restrict__ Cb) {
    __shared__ __align__(16) ushort_t lsA[2][64 * 32];    // [hi/lo], 4 strips
    __shared__ __align__(16) ushort_t lsB[2][128 * 32];   // [hi/lo], 8 strips
    int tid = threadIdx.x;
    int w = tid >> 6, lane = tid & 63;
    int row0 = blockIdx.x * 64;
    int col0 = blockIdx.y * 128;
    int wm = w & 1, wn = w >> 1;
    int lr = lane & 15, lq = lane >> 4;

    // staging: lane covers (row = strip*16 + (lane&15), k-chunk = (lane>>4)*8)
    int srow = lane & 15, sk = (lane >> 4) * 8;
    size_t aoff  = (size_t)(row0 + w * 16 + srow) * 512 + sk;
    size_t boff0 = (size_t)(col0 + (2 * w) * 16 + srow) * 512 + sk;
    size_t boff1 = boff0 + 16 * 512;
    ushort_t* dAh  = &lsA[0][(w * 64 + lane) * 8];
    ushort_t* dAl  = &lsA[1][(w * 64 + lane) * 8];
    ushort_t* dB0h = &lsB[0][((2 * w) * 64 + lane) * 8];
    ushort_t* dB1h = &lsB[0][((2 * w + 1) * 64 + lane) * 8];
    ushort_t* dB0l = &lsB[1][((2 * w) * 64 + lane) * 8];
    ushort_t* dB1l = &lsB[1][((2 * w + 1) * 64 + lane) * 8];

    f32x4 acc[2][4] = {};

    for (int k0 = 0; k0 < 512; k0 += 32) {
        load_lds16(A_hi + aoff + k0, dAh);
        load_lds16(A_lo + aoff + k0, dAl);
        load_lds16(Bt_hi + boff0 + k0, dB0h);
        load_lds16(Bt_hi + boff1 + k0, dB1h);
        load_lds16(Bt_lo + boff0 + k0, dB0l);
        load_lds16(Bt_lo + boff1 + k0, dB1l);
        __syncthreads();

        short8 ah[2], al[2], bh[4], bl[4];
#pragma unroll
        for (int i = 0; i < 2; i++) {
            ah[i] = *(const short8*)&lsA[0][((wm * 2 + i) * 64 + lane) * 8];
            al[i] = *(const short8*)&lsA[1][((wm * 2 + i) * 64 + lane) * 8];
        }
#pragma unroll
        for (int j = 0; j < 4; j++) {
            bh[j] = *(const short8*)&lsB[0][((wn * 4 + j) * 64 + lane) * 8];
            bl[j] = *(const short8*)&lsB[1][((wn * 4 + j) * 64 + lane) * 8];
        }
#pragma unroll
        for (int i = 0; i < 2; i++)
#pragma unroll
            for (int j = 0; j < 4; j++) {
                acc[i][j] = __builtin_amdgcn_mfma_f32_16x16x32_bf16(ah[i], bh[j], acc[i][j], 0, 0, 0);
                acc[i][j] = __builtin_amdgcn_mfma_f32_16x16x32_bf16(ah[i], bl[j], acc[i][j], 0, 0, 0);
                acc[i][j] = __builtin_amdgcn_mfma_f32_16x16x32_bf16(al[i], bh[j], acc[i][j], 0, 0, 0);
            }
        __syncthreads();
    }

    bool sec = (col0 >= 512);                 // block-uniform
    const float* bias = sec ? bias_b : bias_a;
    float* C = sec ? Cb : Ca;
    int cb0 = sec ? col0 - 512 : col0;
    const bool relu = sec ? RELU_B : RELU_A;

#pragma unroll
    for (int i = 0; i < 2; i++)
#pragma unroll
        for (int j = 0; j < 4; j++) {
            int col = cb0 + wn * 64 + j * 16 + lr;
            float bv = bias[col];
#pragma unroll
            for (int r = 0; r < 4; r++) {
                int row = row0 + wm * 32 + i * 16 + lq * 4 + r;
                if (row < N_NODES) {
                    float v = acc[i][j][r] + bv;
                    if (relu) v = fmaxf(v, 0.f);
                    C[(size_t)row * 512 + col] = v;
                }
            }
        }
}

extern "C" void kernel_launch(void* const* d_in, const int* in_sizes, int n_in,
                              void* d_out, int out_size, void* d_ws, size_t ws_size,
                              hipStream_t stream) {
    const float* x  = (const float*)d_in[0];
    const float* W1 = (const float*)d_in[1];
    const float* b1 = (const float*)d_in[2];
    const float* W2 = (const float*)d_in[3];
    const float* b2 = (const float*)d_in[4];
    const float* W3 = (const float*)d_in[5];
    const float* b3 = (const float*)d_in[6];
    const int* src  = (const int*)d_in[7];
    const int* dst  = (const int*)d_in[8];
    float* out = (float*)d_out;

    // workspace layout
    int* wsi = (int*)d_ws;
    int* deg_out  = wsi;                       // 10000
    int* deg_in   = wsi + 10000;               // 10000
    float* norm_out = (float*)(wsi + 20000);   // 10000
    float* norm_in  = (float*)(wsi + 30000);   // 10000
    int* row_ptr  = wsi + 40000;               // 10001 (pad to 10016)
    int* cursor   = wsi + 50016;               // 10000
    int* edge_src = wsi + 60016;               // 160000  -> ends at int 220016
    ushort_t* wt_hi = (ushort_t*)(wsi + 220016);       // 3 * 512*512 ush
    ushort_t* wt_lo = wt_hi + 786432;
    ushort_t* a_hi  = wt_lo + 786432;                  // M_PAD * 512
    ushort_t* a_lo  = a_hi + (size_t)M_PAD * 512;
    // total ~24.6 MB

    // d_out layout: [h4 | h3 | h2]. Stage h1 in the h4 slot (h4 written last).
    float* h4 = out;
    float* h1 = out;
    float* h3 = out + 5120000;
    float* h2 = out + 10240000;

    hipMemsetAsync(d_ws, 0, 20000 * sizeof(int), stream);  // deg_out + deg_in

    deg_kernel<<<(N_EDGES + 255) / 256, 256, 0, stream>>>(src, dst, deg_out, deg_in);
    norm_kernel<<<(N_NODES + 255) / 256, 256, 0, stream>>>(deg_out, deg_in, norm_out, norm_in);
    scan_kernel<<<1, 256, 0, stream>>>(deg_in, row_ptr, cursor);
    fill_kernel<<<(N_EDGES + 255) / 256, 256, 0, stream>>>(src, dst, cursor, edge_src);
    wsplit_kernel<<<dim3(16, 16, 3), dim3(32, 8), 0, stream>>>(W1, W2, W3, wt_hi, wt_lo);

    ushort_t* wt1h = wt_hi;              ushort_t* wt1l = wt_lo;
    ushort_t* wt2h = wt_hi + 262144;     ushort_t* wt2l = wt_lo + 262144;  // W2^T, W3^T contiguous

    dim3 g1(M_PAD / 64, 4);   // N = 512
    dim3 g2(M_PAD / 64, 8);   // N = 1024 (fused h3|h4)

    // layer 1
    agg_kernel<<<M_PAD / 4, 256, 0, stream>>>(x, edge_src, row_ptr, norm_out, norm_in, a_hi, a_lo);
    mfma_gemm<true, true><<<g1, 256, 0, stream>>>(a_hi, a_lo, wt1h, wt1l, b1, b1, h1, h1);
    // layer 2
    agg_kernel<<<M_PAD / 4, 256, 0, stream>>>(h1, edge_src, row_ptr, norm_out, norm_in, a_hi, a_lo);
    mfma_gemm<true, true><<<g1, 256, 0, stream>>>(a_hi, a_lo, wt2h, wt2l, b2, b2, h2, h2);
    // layers 3 & 4 share the aggregation of h2; one fused N=1024 GEMM
    agg_kernel<<<M_PAD / 4, 256, 0, stream>>>(h2, edge_src, row_ptr, norm_out, norm_in, a_hi, a_lo);
    mfma_gemm<true, false><<<g2, 256, 0, stream>>>(a_hi, a_lo, wt2h, wt2l, b2, b3, h3, h4);
}

// Round 4
// 394.734 us; speedup vs baseline: 1.1115x; 1.1115x over previous
//
#include <hip/hip_runtime.h>

#define N_NODES 10000
#define N_EDGES 160000
#define FEAT 512
#define M_PAD 10048   // 157 * 64

typedef unsigned short ushort_t;
typedef unsigned int uint32;

typedef __attribute__((ext_vector_type(8))) short short8;       // 8 bf16 (4 VGPRs)
typedef __attribute__((ext_vector_type(8))) unsigned short ush8;
typedef __attribute__((ext_vector_type(4))) float f32x4;        // MFMA C/D

// ---- tiled ("fragment order") bf16 layout for a R x 512 matrix ----
// strip s = row>>4 (16 rows), k-block kb = k>>5 (32 k). Each (s,kb) is a 1 KB
// tile; ushort offset = s*8192 + kb*512 + (kq*16 + (row&15))*8 + (k&7),
// kq = (k>>3)&3.  A wave staging tile (s,kb) reads global base+lane*16B
// (contiguous 1 KB) and global_load_lds drops lane's 16B at lds_base+lane*16B,
// which is exactly the MFMA A/B fragment order for 16x16x32.

__device__ __forceinline__ ushort_t f2bf(float f) {
    uint32 u = __float_as_uint(f);
    u += 0x7FFF + ((u >> 16) & 1);   // round-to-nearest-even
    return (ushort_t)(u >> 16);
}
__device__ __forceinline__ float bf2f(ushort_t h) {
    return __uint_as_float(((uint32)h) << 16);
}

__device__ __forceinline__ void load_lds16(const ushort_t* g, ushort_t* l) {
    __builtin_amdgcn_global_load_lds(
        (const __attribute__((address_space(1))) void*)g,
        (__attribute__((address_space(3))) void*)l, 16, 0, 0);
}

__device__ __forceinline__ void fma4(float4& a, float w, const float4 v) {
    a.x += w * v.x; a.y += w * v.y; a.z += w * v.z; a.w += w * v.w;
}

// ---------------- degree count ----------------
__global__ void deg_kernel(const int* __restrict__ src, const int* __restrict__ dst,
                           int* __restrict__ deg_out, int* __restrict__ deg_in) {
    int e = blockIdx.x * blockDim.x + threadIdx.x;
    if (e < N_EDGES) {
        atomicAdd(&deg_out[src[e]], 1);
        atomicAdd(&deg_in[dst[e]], 1);
    }
}

// ---------------- norms ----------------
__global__ void norm_kernel(const int* __restrict__ deg_out, const int* __restrict__ deg_in,
                            float* __restrict__ norm_out, float* __restrict__ norm_in) {
    int i = blockIdx.x * blockDim.x + threadIdx.x;
    if (i < N_NODES) {
        int dob = deg_out[i], dib = deg_in[i];
        norm_out[i] = dob > 0 ? rsqrtf((float)dob) : 0.f;
        norm_in[i]  = dib > 0 ? rsqrtf((float)dib) : 0.f;
    }
}

// ---------------- exclusive scan of in-degrees ----------------
__global__ void scan_kernel(const int* __restrict__ deg_in,
                            int* __restrict__ row_ptr, int* __restrict__ cursor) {
    __shared__ int sums[256];
    const int CHUNK = 40;
    int t = threadIdx.x;
    int start = t * CHUNK;
    int s = 0;
    for (int j = 0; j < CHUNK; j++) {
        int i = start + j;
        if (i < N_NODES) s += deg_in[i];
    }
    sums[t] = s;
    __syncthreads();
    for (int off = 1; off < 256; off <<= 1) {
        int v = (t >= off) ? sums[t - off] : 0;
        __syncthreads();
        sums[t] += v;
        __syncthreads();
    }
    int run = (t > 0) ? sums[t - 1] : 0;
    for (int j = 0; j < CHUNK; j++) {
        int i = start + j;
        if (i < N_NODES) {
            row_ptr[i] = run;
            cursor[i] = run;
            run += deg_in[i];
        }
    }
    if (t == 0) row_ptr[N_NODES] = sums[255];
}

// ---------------- CSR fill ----------------
__global__ void fill_kernel(const int* __restrict__ src, const int* __restrict__ dst,
                            int* __restrict__ cursor, int* __restrict__ edge_src) {
    int e = blockIdx.x * blockDim.x + threadIdx.x;
    if (e < N_EDGES) {
        int d = dst[e];
        int pos = atomicAdd(&cursor[d], 1);
        edge_src[pos] = src[e];
    }
}

// ---------------- aggregation: wave per dst, 4x unroll; tiled bf16 hi/lo out --------
__global__ __launch_bounds__(256) void agg_kernel(const float* __restrict__ x,
        const int* __restrict__ edge_src, const int* __restrict__ row_ptr,
        const float* __restrict__ norm_out, const float* __restrict__ norm_in,
        ushort_t* __restrict__ a_hi, ushort_t* __restrict__ a_lo) {
    int lane = threadIdx.x & 63;
    int d = blockIdx.x * 4 + (threadIdx.x >> 6);   // 4 waves/block, one dst each
    float4 aa = make_float4(0.f, 0.f, 0.f, 0.f);
    float4 ab = make_float4(0.f, 0.f, 0.f, 0.f);
    if (d < N_NODES) {
        int beg = row_ptr[d], end = row_ptr[d + 1];
        const float4* xb = ((const float4*)x) + lane * 2;  // lane: feats [lane*8, lane*8+8)
        int e = beg;
        for (; e + 4 <= end; e += 4) {
            int s0 = edge_src[e + 0], s1 = edge_src[e + 1];
            int s2 = edge_src[e + 2], s3 = edge_src[e + 3];
            float w0 = norm_out[s0], w1 = norm_out[s1];
            float w2 = norm_out[s2], w3 = norm_out[s3];
            float4 v0a = xb[s0 * 128], v0b = xb[s0 * 128 + 1];
            float4 v1a = xb[s1 * 128], v1b = xb[s1 * 128 + 1];
            float4 v2a = xb[s2 * 128], v2b = xb[s2 * 128 + 1];
            float4 v3a = xb[s3 * 128], v3b = xb[s3 * 128 + 1];
            fma4(aa, w0, v0a); fma4(ab, w0, v0b);
            fma4(aa, w1, v1a); fma4(ab, w1, v1b);
            fma4(aa, w2, v2a); fma4(ab, w2, v2b);
            fma4(aa, w3, v3a); fma4(ab, w3, v3b);
        }
        for (; e < end; e++) {
            int s = edge_src[e];
            float w = norm_out[s];
            fma4(aa, w, xb[s * 128]);
            fma4(ab, w, xb[s * 128 + 1]);
        }
        float ni = norm_in[d];
        aa.x *= ni; aa.y *= ni; aa.z *= ni; aa.w *= ni;
        ab.x *= ni; ab.y *= ni; ab.z *= ni; ab.w *= ni;
    }
    float vv[8] = {aa.x, aa.y, aa.z, aa.w, ab.x, ab.y, ab.z, ab.w};
    ush8 h8, l8;
#pragma unroll
    for (int i = 0; i < 8; i++) {
        ushort_t h = f2bf(vv[i]);
        h8[i] = h;
        l8[i] = f2bf(vv[i] - bf2f(h));
    }
    // tiled layout: lane's chunk c = lane (k-chunk), kb = lane>>2, kq = lane&3
    size_t o = (size_t)(d >> 4) * 8192 + (size_t)(lane >> 2) * 512
             + (size_t)((lane & 3) * 16 + (d & 15)) * 8;
    *(ush8*)&a_hi[o] = h8;
    *(ush8*)&a_lo[o] = l8;
}

// ---------------- W (KxN fp32) -> tiled W^T hi/lo bf16 ----------------
// One thread per 16B output chunk: chunk = s*1024 + kb*64 + i,
// n = s*16 + (i&15), k0 = kb*32 + (i>>4)*8.
__global__ __launch_bounds__(256) void wsplit_kernel(const float* __restrict__ W1,
        const float* __restrict__ W2, const float* __restrict__ W3,
        ushort_t* __restrict__ wt_hi, ushort_t* __restrict__ wt_lo) {
    const float* W = blockIdx.y == 0 ? W1 : (blockIdx.y == 1 ? W2 : W3);
    size_t mbase = (size_t)blockIdx.y * 262144;
    int chunk = blockIdx.x * 256 + threadIdx.x;    // 0..32767
    int i = chunk & 63;
    int kb = (chunk >> 6) & 15;
    int s = chunk >> 10;
    int n = s * 16 + (i & 15);
    int k0 = kb * 32 + (i >> 4) * 8;
    ush8 h8, l8;
#pragma unroll
    for (int j = 0; j < 8; j++) {
        float v = W[(size_t)(k0 + j) * 512 + n];
        ushort_t h = f2bf(v);
        h8[j] = h;
        l8[j] = f2bf(v - bf2f(h));
    }
    *(ush8*)&wt_hi[mbase + (size_t)chunk * 8] = h8;
    *(ush8*)&wt_lo[mbase + (size_t)chunk * 8] = l8;
}

// ---------------- split-bf16 MFMA GEMM, tiled inputs ----------------
// C = A(M_PAD x 512) @ W(512 x N) + bias.  BM=64, BN=128, BK=32; 4 waves,
// wave tile 32x64 (2x4 16x16 MFMA tiles, 3 split terms each).
// A_hi/A_lo and Bt_hi/Bt_lo are in tiled fragment order (see top comment):
// staging reads contiguous 1 KB per wave-instruction AND fragment ds_reads
// are linear lane*16B (conflict-free).
// Grid: (col-blocks, row-blocks) so consecutive blocks share the A row-panel.
// Dual-output: columns >= 512 go to Cb with bias_b (block-uniform branch).
template <bool RELU_A, bool RELU_B>
__global__ __launch_bounds__(256) void mfma_gemm(
        const ushort_t* __restrict__ A_hi, const ushort_t* __restrict__ A_lo,
        const ushort_t* __restrict__ Bt_hi, const ushort_t* __restrict__ Bt_lo,
        const float* __restrict__ bias_a, const float* __restrict__ bias_b,
        float* __restrict__ Ca, float* __restrict__ Cb) {
    __shared__ __align__(16) ushort_t lsA[2][64 * 32];    // [hi/lo], 4 strips
    __shared__ __align__(16) ushort_t lsB[2][128 * 32];   // [hi/lo], 8 strips
    int tid = threadIdx.x;
    int w = tid >> 6, lane = tid & 63;
    int col0 = blockIdx.x * 128;
    int row0 = blockIdx.y * 64;
    int wm = w & 1, wn = w >> 1;
    int lr = lane & 15, lq = lane >> 4;

    // tiled staging: strip stride 8192 ush, kb stride 512 ush, lane*8 within
    size_t aoff = (size_t)((row0 >> 4) + w) * 8192 + lane * 8;
    size_t boff = (size_t)((col0 >> 4) + 2 * w) * 8192 + lane * 8;
    ushort_t* dAh  = &lsA[0][(w * 64 + lane) * 8];
    ushort_t* dAl  = &lsA[1][(w * 64 + lane) * 8];
    ushort_t* dB0h = &lsB[0][((2 * w) * 64 + lane) * 8];
    ushort_t* dB1h = &lsB[0][((2 * w + 1) * 64 + lane) * 8];
    ushort_t* dB0l = &lsB[1][((2 * w) * 64 + lane) * 8];
    ushort_t* dB1l = &lsB[1][((2 * w + 1) * 64 + lane) * 8];

    f32x4 acc[2][4] = {};

    for (int kb = 0; kb < 16; kb++) {
        size_t ko = (size_t)kb * 512;
        load_lds16(A_hi + aoff + ko, dAh);
        load_lds16(A_lo + aoff + ko, dAl);
        load_lds16(Bt_hi + boff + ko, dB0h);
        load_lds16(Bt_hi + boff + 8192 + ko, dB1h);
        load_lds16(Bt_lo + boff + ko, dB0l);
        load_lds16(Bt_lo + boff + 8192 + ko, dB1l);
        __syncthreads();

        short8 ah[2], al[2], bh[4], bl[4];
#pragma unroll
        for (int i = 0; i < 2; i++) {
            ah[i] = *(const short8*)&lsA[0][((wm * 2 + i) * 64 + lane) * 8];
            al[i] = *(const short8*)&lsA[1][((wm * 2 + i) * 64 + lane) * 8];
        }
#pragma unroll
        for (int j = 0; j < 4; j++) {
            bh[j] = *(const short8*)&lsB[0][((wn * 4 + j) * 64 + lane) * 8];
            bl[j] = *(const short8*)&lsB[1][((wn * 4 + j) * 64 + lane) * 8];
        }
#pragma unroll
        for (int i = 0; i < 2; i++)
#pragma unroll
            for (int j = 0; j < 4; j++) {
                acc[i][j] = __builtin_amdgcn_mfma_f32_16x16x32_bf16(ah[i], bh[j], acc[i][j], 0, 0, 0);
                acc[i][j] = __builtin_amdgcn_mfma_f32_16x16x32_bf16(ah[i], bl[j], acc[i][j], 0, 0, 0);
                acc[i][j] = __builtin_amdgcn_mfma_f32_16x16x32_bf16(al[i], bh[j], acc[i][j], 0, 0, 0);
            }
        __syncthreads();
    }

    bool sec = (col0 >= 512);                 // block-uniform
    const float* bias = sec ? bias_b : bias_a;
    float* C = sec ? Cb : Ca;
    int cb0 = sec ? col0 - 512 : col0;
    const bool relu = sec ? RELU_B : RELU_A;

#pragma unroll
    for (int i = 0; i < 2; i++)
#pragma unroll
        for (int j = 0; j < 4; j++) {
            int col = cb0 + wn * 64 + j * 16 + lr;
            float bv = bias[col];
#pragma unroll
            for (int r = 0; r < 4; r++) {
                int row = row0 + wm * 32 + i * 16 + lq * 4 + r;
                if (row < N_NODES) {
                    float v = acc[i][j][r] + bv;
                    if (relu) v = fmaxf(v, 0.f);
                    C[(size_t)row * 512 + col] = v;
                }
            }
        }
}

extern "C" void kernel_launch(void* const* d_in, const int* in_sizes, int n_in,
                              void* d_out, int out_size, void* d_ws, size_t ws_size,
                              hipStream_t stream) {
    const float* x  = (const float*)d_in[0];
    const float* W1 = (const float*)d_in[1];
    const float* b1 = (const float*)d_in[2];
    const float* W2 = (const float*)d_in[3];
    const float* b2 = (const float*)d_in[4];
    const float* W3 = (const float*)d_in[5];
    const float* b3 = (const float*)d_in[6];
    const int* src  = (const int*)d_in[7];
    const int* dst  = (const int*)d_in[8];
    float* out = (float*)d_out;

    // workspace layout
    int* wsi = (int*)d_ws;
    int* deg_out  = wsi;                       // 10000
    int* deg_in   = wsi + 10000;               // 10000
    float* norm_out = (float*)(wsi + 20000);   // 10000
    float* norm_in  = (float*)(wsi + 30000);   // 10000
    int* row_ptr  = wsi + 40000;               // 10001 (pad to 10016)
    int* cursor   = wsi + 50016;               // 10000
    int* edge_src = wsi + 60016;               // 160000  -> ends at int 220016
    ushort_t* wt_hi = (ushort_t*)(wsi + 220016);       // 3 * 262144 ush (tiled)
    ushort_t* wt_lo = wt_hi + 786432;
    ushort_t* a_hi  = wt_lo + 786432;                  // M_PAD * 512 (tiled)
    ushort_t* a_lo  = a_hi + (size_t)M_PAD * 512;
    // total ~24.6 MB

    // d_out layout: [h4 | h3 | h2]. Stage h1 in the h4 slot (h4 written last).
    float* h4 = out;
    float* h1 = out;
    float* h3 = out + 5120000;
    float* h2 = out + 10240000;

    hipMemsetAsync(d_ws, 0, 20000 * sizeof(int), stream);  // deg_out + deg_in

    deg_kernel<<<(N_EDGES + 255) / 256, 256, 0, stream>>>(src, dst, deg_out, deg_in);
    norm_kernel<<<(N_NODES + 255) / 256, 256, 0, stream>>>(deg_out, deg_in, norm_out, norm_in);
    scan_kernel<<<1, 256, 0, stream>>>(deg_in, row_ptr, cursor);
    fill_kernel<<<(N_EDGES + 255) / 256, 256, 0, stream>>>(src, dst, cursor, edge_src);
    wsplit_kernel<<<dim3(128, 3), 256, 0, stream>>>(W1, W2, W3, wt_hi, wt_lo);

    ushort_t* wt1h = wt_hi;              ushort_t* wt1l = wt_lo;
    ushort_t* wt2h = wt_hi + 262144;     ushort_t* wt2l = wt_lo + 262144;  // W2^T, W3^T contiguous

    dim3 g1(4, M_PAD / 64);   // N = 512   (col-blocks fast -> A-panel reuse)
    dim3 g2(8, M_PAD / 64);   // N = 1024  (fused h3|h4)

    // layer 1
    agg_kernel<<<M_PAD / 4, 256, 0, stream>>>(x, edge_src, row_ptr, norm_out, norm_in, a_hi, a_lo);
    mfma_gemm<true, true><<<g1, 256, 0, stream>>>(a_hi, a_lo, wt1h, wt1l, b1, b1, h1, h1);
    // layer 2
    agg_kernel<<<M_PAD / 4, 256, 0, stream>>>(h1, edge_src, row_ptr, norm_out, norm_in, a_hi, a_lo);
    mfma_gemm<true, true><<<g1, 256, 0, stream>>>(a_hi, a_lo, wt2h, wt2l, b2, b2, h2, h2);
    // layers 3 & 4 share the aggregation of h2; one fused N=1024 GEMM
    agg_kernel<<<M_PAD / 4, 256, 0, stream>>>(h2, edge_src, row_ptr, norm_out, norm_in, a_hi, a_lo);
    mfma_gemm<true, false><<<g2, 256, 0, stream>>>(a_hi, a_lo, wt2h, wt2l, b2, b3, h3, h4);
}

// Round 5
// 357.942 us; speedup vs baseline: 1.2258x; 1.1028x over previous
//
#include <hip/hip_runtime.h>

#define N_NODES 10000
#define N_EDGES 160000
#define FEAT 512
#define M_PAD 10048   // 157 * 64

typedef unsigned short ushort_t;
typedef unsigned int uint32;

typedef __attribute__((ext_vector_type(8))) short short8;       // 8 bf16 (4 VGPRs)
typedef __attribute__((ext_vector_type(8))) unsigned short ush8;
typedef __attribute__((ext_vector_type(8))) _Float16 half8;     // 16 B
typedef __attribute__((ext_vector_type(4))) float f32x4;        // MFMA C/D

// ---- tiled ("fragment order") bf16 layout for a R x 512 matrix ----
// strip s = row>>4 (16 rows), k-block kb = k>>5 (32 k). Each (s,kb) is a 1 KB
// tile; ushort offset = s*8192 + kb*512 + (kq*16 + (row&15))*8 + (k&7),
// kq = (k>>3)&3.  A wave staging tile (s,kb) reads global base+lane*16B
// (contiguous 1 KB) and global_load_lds drops lane's 16B at lds_base+lane*16B,
// which is exactly the MFMA A/B fragment order for 16x16x32.

__device__ __forceinline__ ushort_t f2bf(float f) {
    uint32 u = __float_as_uint(f);
    u += 0x7FFF + ((u >> 16) & 1);   // round-to-nearest-even
    return (ushort_t)(u >> 16);
}
__device__ __forceinline__ float bf2f(ushort_t h) {
    return __uint_as_float(((uint32)h) << 16);
}

__device__ __forceinline__ void load_lds16(const ushort_t* g, ushort_t* l) {
    __builtin_amdgcn_global_load_lds(
        (const __attribute__((address_space(1))) void*)g,
        (__attribute__((address_space(3))) void*)l, 16, 0, 0);
}

// ---------------- degree count ----------------
__global__ void deg_kernel(const int* __restrict__ src, const int* __restrict__ dst,
                           int* __restrict__ deg_out, int* __restrict__ deg_in) {
    int e = blockIdx.x * blockDim.x + threadIdx.x;
    if (e < N_EDGES) {
        atomicAdd(&deg_out[src[e]], 1);
        atomicAdd(&deg_in[dst[e]], 1);
    }
}

// ---------------- norms ----------------
__global__ void norm_kernel(const int* __restrict__ deg_out, const int* __restrict__ deg_in,
                            float* __restrict__ norm_out, float* __restrict__ norm_in) {
    int i = blockIdx.x * blockDim.x + threadIdx.x;
    if (i < N_NODES) {
        int dob = deg_out[i], dib = deg_in[i];
        norm_out[i] = dob > 0 ? rsqrtf((float)dob) : 0.f;
        norm_in[i]  = dib > 0 ? rsqrtf((float)dib) : 0.f;
    }
}

// ---------------- exclusive scan of in-degrees ----------------
__global__ void scan_kernel(const int* __restrict__ deg_in,
                            int* __restrict__ row_ptr, int* __restrict__ cursor) {
    __shared__ int sums[256];
    const int CHUNK = 40;
    int t = threadIdx.x;
    int start = t * CHUNK;
    int s = 0;
    for (int j = 0; j < CHUNK; j++) {
        int i = start + j;
        if (i < N_NODES) s += deg_in[i];
    }
    sums[t] = s;
    __syncthreads();
    for (int off = 1; off < 256; off <<= 1) {
        int v = (t >= off) ? sums[t - off] : 0;
        __syncthreads();
        sums[t] += v;
        __syncthreads();
    }
    int run = (t > 0) ? sums[t - 1] : 0;
    for (int j = 0; j < CHUNK; j++) {
        int i = start + j;
        if (i < N_NODES) {
            row_ptr[i] = run;
            cursor[i] = run;
            run += deg_in[i];
        }
    }
    if (t == 0) row_ptr[N_NODES] = sums[255];
}

// ---------------- CSR fill ----------------
__global__ void fill_kernel(const int* __restrict__ src, const int* __restrict__ dst,
                            int* __restrict__ cursor, int* __restrict__ edge_src) {
    int e = blockIdx.x * blockDim.x + threadIdx.x;
    if (e < N_EDGES) {
        int d = dst[e];
        int pos = atomicAdd(&cursor[d], 1);
        edge_src[pos] = src[e];
    }
}

// ---------------- prescale: xs[i] = fp16(x[i] * norm_out[i]) ----------------
__global__ __launch_bounds__(256) void prescale_kernel(const float* __restrict__ x,
        const float* __restrict__ norm_out, _Float16* __restrict__ xs) {
    int idx = blockIdx.x * 256 + threadIdx.x;     // one per 8 floats
    if (idx >= N_NODES * 64) return;
    int node = idx >> 6, f8 = idx & 63;
    float w = norm_out[node];
    const float4* p = (const float4*)&x[(size_t)node * 512 + f8 * 8];
    float4 a = p[0], b = p[1];
    half8 h;
    h[0] = (_Float16)(a.x * w); h[1] = (_Float16)(a.y * w);
    h[2] = (_Float16)(a.z * w); h[3] = (_Float16)(a.w * w);
    h[4] = (_Float16)(b.x * w); h[5] = (_Float16)(b.y * w);
    h[6] = (_Float16)(b.z * w); h[7] = (_Float16)(b.w * w);
    *(half8*)&xs[(size_t)node * 512 + f8 * 8] = h;
}

// ---------------- aggregation v3: one wave per dst, fp16 pre-scaled gather ----------
// out[d] = norm_in[d] * sum xs[s];  epilogue writes tiled bf16 hi/lo split.
// block = 64 threads so d is wave-uniform -> scalar edge/rowptr loads.
__global__ __launch_bounds__(64) void agg_kernel(const _Float16* __restrict__ xs,
        const int* __restrict__ edge_src, const int* __restrict__ row_ptr,
        const float* __restrict__ norm_in,
        ushort_t* __restrict__ a_hi, ushort_t* __restrict__ a_lo) {
    int lane = threadIdx.x;
    int d = blockIdx.x;
    float acc[8] = {};
    if (d < N_NODES) {
        int beg = row_ptr[d], end = row_ptr[d + 1];
        const _Float16* xb = xs + lane * 8;     // lane: feats [lane*8, lane*8+8)
        int e = beg;
        for (; e + 8 <= end; e += 8) {
            int s0 = edge_src[e + 0], s1 = edge_src[e + 1];
            int s2 = edge_src[e + 2], s3 = edge_src[e + 3];
            int s4 = edge_src[e + 4], s5 = edge_src[e + 5];
            int s6 = edge_src[e + 6], s7 = edge_src[e + 7];
            half8 v0 = *(const half8*)&xb[(size_t)s0 * 512];
            half8 v1 = *(const half8*)&xb[(size_t)s1 * 512];
            half8 v2 = *(const half8*)&xb[(size_t)s2 * 512];
            half8 v3 = *(const half8*)&xb[(size_t)s3 * 512];
            half8 v4 = *(const half8*)&xb[(size_t)s4 * 512];
            half8 v5 = *(const half8*)&xb[(size_t)s5 * 512];
            half8 v6 = *(const half8*)&xb[(size_t)s6 * 512];
            half8 v7 = *(const half8*)&xb[(size_t)s7 * 512];
#pragma unroll
            for (int i = 0; i < 8; i++) {
                acc[i] += (float)v0[i] + (float)v1[i];
                acc[i] += (float)v2[i] + (float)v3[i];
                acc[i] += (float)v4[i] + (float)v5[i];
                acc[i] += (float)v6[i] + (float)v7[i];
            }
        }
        for (; e < end; e++) {
            int s = edge_src[e];
            half8 v = *(const half8*)&xb[(size_t)s * 512];
#pragma unroll
            for (int i = 0; i < 8; i++) acc[i] += (float)v[i];
        }
        float ni = norm_in[d];
#pragma unroll
        for (int i = 0; i < 8; i++) acc[i] *= ni;
    }
    ush8 h8, l8;
#pragma unroll
    for (int i = 0; i < 8; i++) {
        ushort_t h = f2bf(acc[i]);
        h8[i] = h;
        l8[i] = f2bf(acc[i] - bf2f(h));
    }
    // tiled layout: kb = lane>>2, kq = lane&3
    size_t o = (size_t)(d >> 4) * 8192 + (size_t)(lane >> 2) * 512
             + (size_t)((lane & 3) * 16 + (d & 15)) * 8;
    *(ush8*)&a_hi[o] = h8;
    *(ush8*)&a_lo[o] = l8;
}

// ---------------- W (KxN fp32) -> tiled W^T hi/lo bf16 ----------------
__global__ __launch_bounds__(256) void wsplit_kernel(const float* __restrict__ W1,
        const float* __restrict__ W2, const float* __restrict__ W3,
        ushort_t* __restrict__ wt_hi, ushort_t* __restrict__ wt_lo) {
    const float* W = blockIdx.y == 0 ? W1 : (blockIdx.y == 1 ? W2 : W3);
    size_t mbase = (size_t)blockIdx.y * 262144;
    int chunk = blockIdx.x * 256 + threadIdx.x;    // 0..32767
    int i = chunk & 63;
    int kb = (chunk >> 6) & 15;
    int s = chunk >> 10;
    int n = s * 16 + (i & 15);
    int k0 = kb * 32 + (i >> 4) * 8;
    ush8 h8, l8;
#pragma unroll
    for (int j = 0; j < 8; j++) {
        float v = W[(size_t)(k0 + j) * 512 + n];
        ushort_t h = f2bf(v);
        h8[j] = h;
        l8[j] = f2bf(v - bf2f(h));
    }
    *(ush8*)&wt_hi[mbase + (size_t)chunk * 8] = h8;
    *(ush8*)&wt_lo[mbase + (size_t)chunk * 8] = l8;
}

// ---------------- split-bf16 MFMA GEMM, tiled inputs ----------------
// C = A(M_PAD x 512) @ W(512 x N) + bias.  BM=64, BN=128, BK=32; 4 waves,
// wave tile 32x64 (2x4 16x16 MFMA tiles, 3 split terms each).
// WRITE_C: store fp32 C.  WRITE_XS: store xs = fp16(relu_out * norm_out[row])
// (the pre-scaled gather source for the next aggregation).
// Dual-output on columns >= 512 (block-uniform): Cb / bias_b / RELU_B.
template <bool RELU_A, bool RELU_B, bool WRITE_C, bool WRITE_XS>
__global__ __launch_bounds__(256) void mfma_gemm(
        const ushort_t* __restrict__ A_hi, const ushort_t* __restrict__ A_lo,
        const ushort_t* __restrict__ Bt_hi, const ushort_t* __restrict__ Bt_lo,
        const float* __restrict__ bias_a, const float* __restrict__ bias_b,
        const float* __restrict__ norm_out,
        float* __restrict__ Ca, float* __restrict__ Cb,
        _Float16* __restrict__ xs) {
    __shared__ __align__(16) ushort_t lsA[2][64 * 32];    // [hi/lo], 4 strips
    __shared__ __align__(16) ushort_t lsB[2][128 * 32];   // [hi/lo], 8 strips
    int tid = threadIdx.x;
    int w = tid >> 6, lane = tid & 63;
    int col0 = blockIdx.x * 128;
    int row0 = blockIdx.y * 64;
    int wm = w & 1, wn = w >> 1;
    int lr = lane & 15, lq = lane >> 4;

    size_t aoff = (size_t)((row0 >> 4) + w) * 8192 + lane * 8;
    size_t boff = (size_t)((col0 >> 4) + 2 * w) * 8192 + lane * 8;
    ushort_t* dAh  = &lsA[0][(w * 64 + lane) * 8];
    ushort_t* dAl  = &lsA[1][(w * 64 + lane) * 8];
    ushort_t* dB0h = &lsB[0][((2 * w) * 64 + lane) * 8];
    ushort_t* dB1h = &lsB[0][((2 * w + 1) * 64 + lane) * 8];
    ushort_t* dB0l = &lsB[1][((2 * w) * 64 + lane) * 8];
    ushort_t* dB1l = &lsB[1][((2 * w + 1) * 64 + lane) * 8];

    f32x4 acc[2][4] = {};

    for (int kb = 0; kb < 16; kb++) {
        size_t ko = (size_t)kb * 512;
        load_lds16(A_hi + aoff + ko, dAh);
        load_lds16(A_lo + aoff + ko, dAl);
        load_lds16(Bt_hi + boff + ko, dB0h);
        load_lds16(Bt_hi + boff + 8192 + ko, dB1h);
        load_lds16(Bt_lo + boff + ko, dB0l);
        load_lds16(Bt_lo + boff + 8192 + ko, dB1l);
        __syncthreads();

        short8 ah[2], al[2], bh[4], bl[4];
#pragma unroll
        for (int i = 0; i < 2; i++) {
            ah[i] = *(const short8*)&lsA[0][((wm * 2 + i) * 64 + lane) * 8];
            al[i] = *(const short8*)&lsA[1][((wm * 2 + i) * 64 + lane) * 8];
        }
#pragma unroll
        for (int j = 0; j < 4; j++) {
            bh[j] = *(const short8*)&lsB[0][((wn * 4 + j) * 64 + lane) * 8];
            bl[j] = *(const short8*)&lsB[1][((wn * 4 + j) * 64 + lane) * 8];
        }
#pragma unroll
        for (int i = 0; i < 2; i++)
#pragma unroll
            for (int j = 0; j < 4; j++) {
                acc[i][j] = __builtin_amdgcn_mfma_f32_16x16x32_bf16(ah[i], bh[j], acc[i][j], 0, 0, 0);
                acc[i][j] = __builtin_amdgcn_mfma_f32_16x16x32_bf16(ah[i], bl[j], acc[i][j], 0, 0, 0);
                acc[i][j] = __builtin_amdgcn_mfma_f32_16x16x32_bf16(al[i], bh[j], acc[i][j], 0, 0, 0);
            }
        __syncthreads();
    }

    bool sec = (col0 >= 512);                 // block-uniform
    const float* bias = sec ? bias_b : bias_a;
    float* C = sec ? Cb : Ca;
    int cb0 = sec ? col0 - 512 : col0;
    const bool relu = sec ? RELU_B : RELU_A;

#pragma unroll
    for (int i = 0; i < 2; i++)
#pragma unroll
        for (int j = 0; j < 4; j++) {
            int col = cb0 + wn * 64 + j * 16 + lr;
            float bv = bias[col];
#pragma unroll
            for (int r = 0; r < 4; r++) {
                int row = row0 + wm * 32 + i * 16 + lq * 4 + r;
                if (row < N_NODES) {
                    float v = acc[i][j][r] + bv;
                    if (relu) v = fmaxf(v, 0.f);
                    if (WRITE_C) C[(size_t)row * 512 + col] = v;
                    if (WRITE_XS)
                        xs[(size_t)row * 512 + col] = (_Float16)(v * norm_out[row]);
                }
            }
        }
}

extern "C" void kernel_launch(void* const* d_in, const int* in_sizes, int n_in,
                              void* d_out, int out_size, void* d_ws, size_t ws_size,
                              hipStream_t stream) {
    const float* x  = (const float*)d_in[0];
    const float* W1 = (const float*)d_in[1];
    const float* b1 = (const float*)d_in[2];
    const float* W2 = (const float*)d_in[3];
    const float* b2 = (const float*)d_in[4];
    const float* W3 = (const float*)d_in[5];
    const float* b3 = (const float*)d_in[6];
    const int* src  = (const int*)d_in[7];
    const int* dst  = (const int*)d_in[8];
    float* out = (float*)d_out;

    // workspace layout
    int* wsi = (int*)d_ws;
    int* deg_out  = wsi;                       // 10000
    int* deg_in   = wsi + 10000;               // 10000
    float* norm_out = (float*)(wsi + 20000);   // 10000
    float* norm_in  = (float*)(wsi + 30000);   // 10000
    int* row_ptr  = wsi + 40000;               // 10001 (pad to 10016)
    int* cursor   = wsi + 50016;               // 10000
    int* edge_src = wsi + 60016;               // 160000  -> ends at int 220016
    ushort_t* wt_hi = (ushort_t*)(wsi + 220016);       // 3 * 262144 ush (tiled)
    ushort_t* wt_lo = wt_hi + 786432;
    ushort_t* a_hi  = wt_lo + 786432;                  // M_PAD * 512 (tiled)
    ushort_t* a_lo  = a_hi + (size_t)M_PAD * 512;
    _Float16* xs    = (_Float16*)(a_lo + (size_t)M_PAD * 512);  // N_NODES*512
    // total ~34.9 MB

    // d_out layout: [h4 | h3 | h2]
    float* h4 = out;
    float* h3 = out + 5120000;
    float* h2 = out + 10240000;

    hipMemsetAsync(d_ws, 0, 20000 * sizeof(int), stream);  // deg_out + deg_in

    deg_kernel<<<(N_EDGES + 255) / 256, 256, 0, stream>>>(src, dst, deg_out, deg_in);
    norm_kernel<<<(N_NODES + 255) / 256, 256, 0, stream>>>(deg_out, deg_in, norm_out, norm_in);
    scan_kernel<<<1, 256, 0, stream>>>(deg_in, row_ptr, cursor);
    fill_kernel<<<(N_EDGES + 255) / 256, 256, 0, stream>>>(src, dst, cursor, edge_src);
    wsplit_kernel<<<dim3(128, 3), 256, 0, stream>>>(W1, W2, W3, wt_hi, wt_lo);
    prescale_kernel<<<(N_NODES * 64 + 255) / 256, 256, 0, stream>>>(x, norm_out, xs);

    ushort_t* wt1h = wt_hi;              ushort_t* wt1l = wt_lo;
    ushort_t* wt2h = wt_hi + 262144;     ushort_t* wt2l = wt_lo + 262144;  // W2^T|W3^T contiguous

    dim3 g1(4, M_PAD / 64);   // N = 512   (col-blocks fast -> A-panel reuse)
    dim3 g2(8, M_PAD / 64);   // N = 1024  (fused h3|h4)

    // layer 1: h1 never materialized in fp32 — GEMM writes xs only
    agg_kernel<<<M_PAD, 64, 0, stream>>>(xs, edge_src, row_ptr, norm_in, a_hi, a_lo);
    mfma_gemm<true, true, false, true><<<g1, 256, 0, stream>>>(
        a_hi, a_lo, wt1h, wt1l, b1, b1, norm_out, h2, h2, xs);
    // layer 2: h2 is an output AND feeds agg3 via xs
    agg_kernel<<<M_PAD, 64, 0, stream>>>(xs, edge_src, row_ptr, norm_in, a_hi, a_lo);
    mfma_gemm<true, true, true, true><<<g1, 256, 0, stream>>>(
        a_hi, a_lo, wt2h, wt2l, b2, b2, norm_out, h2, h2, xs);
    // layers 3 & 4 share the aggregation of h2; one fused N=1024 GEMM
    agg_kernel<<<M_PAD, 64, 0, stream>>>(xs, edge_src, row_ptr, norm_in, a_hi, a_lo);
    mfma_gemm<true, false, true, false><<<g2, 256, 0, stream>>>(
        a_hi, a_lo, wt2h, wt2l, b2, b3, norm_out, h3, h4, xs);
}

// Round 6
// 337.048 us; speedup vs baseline: 1.3017x; 1.0620x over previous
//
#include <hip/hip_runtime.h>

#define N_NODES 10000
#define N_EDGES 160000
#define FEAT 512
#define M_PAD 10048   // 157 * 64

typedef unsigned short ushort_t;
typedef unsigned int uint32;

typedef __attribute__((ext_vector_type(8))) _Float16 half8;     // 16 B = MFMA A/B frag
typedef __attribute__((ext_vector_type(4))) float f32x4;        // MFMA C/D

// ---- tiled ("fragment order") fp16 layout for a R x 512 matrix ----
// strip s = row>>4 (16 rows), k-block kb = k>>5 (32 k). Each (s,kb) is a 1 KB
// tile; half-elem offset = s*8192 + kb*512 + (kq*16 + (row&15))*8 + (k&7),
// kq = (k>>3)&3.  A wave staging tile (s,kb) reads global base+lane*16B
// (contiguous 1 KB) and global_load_lds drops lane's 16B at lds_base+lane*16B,
// which is exactly the MFMA A/B fragment order for 16x16x32.

__device__ __forceinline__ void load_lds16(const void* g, void* l) {
    __builtin_amdgcn_global_load_lds(
        (const __attribute__((address_space(1))) void*)g,
        (__attribute__((address_space(3))) void*)l, 16, 0, 0);
}

// ---------------- degree count ----------------
__global__ void deg_kernel(const int* __restrict__ src, const int* __restrict__ dst,
                           int* __restrict__ deg_out, int* __restrict__ deg_in) {
    int e = blockIdx.x * blockDim.x + threadIdx.x;
    if (e < N_EDGES) {
        atomicAdd(&deg_out[src[e]], 1);
        atomicAdd(&deg_in[dst[e]], 1);
    }
}

// ---------------- norms ----------------
__global__ void norm_kernel(const int* __restrict__ deg_out, const int* __restrict__ deg_in,
                            float* __restrict__ norm_out, float* __restrict__ norm_in) {
    int i = blockIdx.x * blockDim.x + threadIdx.x;
    if (i < N_NODES) {
        int dob = deg_out[i], dib = deg_in[i];
        norm_out[i] = dob > 0 ? rsqrtf((float)dob) : 0.f;
        norm_in[i]  = dib > 0 ? rsqrtf((float)dib) : 0.f;
    }
}

// ---------------- exclusive scan of in-degrees ----------------
__global__ void scan_kernel(const int* __restrict__ deg_in,
                            int* __restrict__ row_ptr, int* __restrict__ cursor) {
    __shared__ int sums[256];
    const int CHUNK = 40;
    int t = threadIdx.x;
    int start = t * CHUNK;
    int s = 0;
    for (int j = 0; j < CHUNK; j++) {
        int i = start + j;
        if (i < N_NODES) s += deg_in[i];
    }
    sums[t] = s;
    __syncthreads();
    for (int off = 1; off < 256; off <<= 1) {
        int v = (t >= off) ? sums[t - off] : 0;
        __syncthreads();
        sums[t] += v;
        __syncthreads();
    }
    int run = (t > 0) ? sums[t - 1] : 0;
    for (int j = 0; j < CHUNK; j++) {
        int i = start + j;
        if (i < N_NODES) {
            row_ptr[i] = run;
            cursor[i] = run;
            run += deg_in[i];
        }
    }
    if (t == 0) row_ptr[N_NODES] = sums[255];
}

// ---------------- CSR fill ----------------
__global__ void fill_kernel(const int* __restrict__ src, const int* __restrict__ dst,
                            int* __restrict__ cursor, int* __restrict__ edge_src) {
    int e = blockIdx.x * blockDim.x + threadIdx.x;
    if (e < N_EDGES) {
        int d = dst[e];
        int pos = atomicAdd(&cursor[d], 1);
        edge_src[pos] = src[e];
    }
}

// ---------------- prescale: xs[i] = fp16(x[i] * norm_out[i]) ----------------
__global__ __launch_bounds__(256) void prescale_kernel(const float* __restrict__ x,
        const float* __restrict__ norm_out, _Float16* __restrict__ xs) {
    int idx = blockIdx.x * 256 + threadIdx.x;     // one per 8 floats
    if (idx >= N_NODES * 64) return;
    int node = idx >> 6, f8 = idx & 63;
    float w = norm_out[node];
    const float4* p = (const float4*)&x[(size_t)node * 512 + f8 * 8];
    float4 a = p[0], b = p[1];
    half8 h;
    h[0] = (_Float16)(a.x * w); h[1] = (_Float16)(a.y * w);
    h[2] = (_Float16)(a.z * w); h[3] = (_Float16)(a.w * w);
    h[4] = (_Float16)(b.x * w); h[5] = (_Float16)(b.y * w);
    h[6] = (_Float16)(b.z * w); h[7] = (_Float16)(b.w * w);
    *(half8*)&xs[(size_t)node * 512 + f8 * 8] = h;
}

// ---------------- aggregation: one wave per dst, fp16 pre-scaled gather ----------
// out[d] = norm_in[d] * sum xs[s];  epilogue writes tiled fp16 hi/lo split.
__global__ __launch_bounds__(64) void agg_kernel(const _Float16* __restrict__ xs,
        const int* __restrict__ edge_src, const int* __restrict__ row_ptr,
        const float* __restrict__ norm_in,
        _Float16* __restrict__ a_hi, _Float16* __restrict__ a_lo) {
    int lane = threadIdx.x;
    int d = blockIdx.x;
    float acc[8] = {};
    if (d < N_NODES) {
        int beg = row_ptr[d], end = row_ptr[d + 1];
        const _Float16* xb = xs + lane * 8;     // lane: feats [lane*8, lane*8+8)
        int e = beg;
        for (; e + 8 <= end; e += 8) {
            int s0 = edge_src[e + 0], s1 = edge_src[e + 1];
            int s2 = edge_src[e + 2], s3 = edge_src[e + 3];
            int s4 = edge_src[e + 4], s5 = edge_src[e + 5];
            int s6 = edge_src[e + 6], s7 = edge_src[e + 7];
            half8 v0 = *(const half8*)&xb[(size_t)s0 * 512];
            half8 v1 = *(const half8*)&xb[(size_t)s1 * 512];
            half8 v2 = *(const half8*)&xb[(size_t)s2 * 512];
            half8 v3 = *(const half8*)&xb[(size_t)s3 * 512];
            half8 v4 = *(const half8*)&xb[(size_t)s4 * 512];
            half8 v5 = *(const half8*)&xb[(size_t)s5 * 512];
            half8 v6 = *(const half8*)&xb[(size_t)s6 * 512];
            half8 v7 = *(const half8*)&xb[(size_t)s7 * 512];
#pragma unroll
            for (int i = 0; i < 8; i++) {
                acc[i] += (float)v0[i] + (float)v1[i];
                acc[i] += (float)v2[i] + (float)v3[i];
                acc[i] += (float)v4[i] + (float)v5[i];
                acc[i] += (float)v6[i] + (float)v7[i];
            }
        }
        for (; e < end; e++) {
            int s = edge_src[e];
            half8 v = *(const half8*)&xb[(size_t)s * 512];
#pragma unroll
            for (int i = 0; i < 8; i++) acc[i] += (float)v[i];
        }
        float ni = norm_in[d];
#pragma unroll
        for (int i = 0; i < 8; i++) acc[i] *= ni;
    }
    half8 h8, l8;
#pragma unroll
    for (int i = 0; i < 8; i++) {
        _Float16 h = (_Float16)acc[i];
        h8[i] = h;
        l8[i] = (_Float16)(acc[i] - (float)h);
    }
    // tiled layout: kb = lane>>2, kq = lane&3
    size_t o = (size_t)(d >> 4) * 8192 + (size_t)(lane >> 2) * 512
             + (size_t)((lane & 3) * 16 + (d & 15)) * 8;
    *(half8*)&a_hi[o] = h8;
    *(half8*)&a_lo[o] = l8;
}

// ---------------- W (KxN fp32) -> tiled W^T fp16 (single precision: weights are
// small-magnitude Glorot values, fp16 RTE error ~2^-12 relative) ----------------
__global__ __launch_bounds__(256) void wsplit_kernel(const float* __restrict__ W1,
        const float* __restrict__ W2, const float* __restrict__ W3,
        _Float16* __restrict__ wt) {
    const float* W = blockIdx.y == 0 ? W1 : (blockIdx.y == 1 ? W2 : W3);
    size_t mbase = (size_t)blockIdx.y * 262144;
    int chunk = blockIdx.x * 256 + threadIdx.x;    // 0..32767
    int i = chunk & 63;
    int kb = (chunk >> 6) & 15;
    int s = chunk >> 10;
    int n = s * 16 + (i & 15);
    int k0 = kb * 32 + (i >> 4) * 8;
    half8 h8;
#pragma unroll
    for (int j = 0; j < 8; j++)
        h8[j] = (_Float16)W[(size_t)(k0 + j) * 512 + n];
    *(half8*)&wt[mbase + (size_t)chunk * 8] = h8;
}

// ---------------- 2-term fp16 MFMA GEMM, tiled inputs ----------------
// C = A(M_PAD x 512) @ W(512 x N) + bias.  BM=64, BN=128, BK=32; 4 waves,
// wave tile 32x64 (2x4 16x16 MFMA tiles, 2 split terms: A_hi*B + A_lo*B).
// A_hi/A_lo (fp16 2-term split) and Bt (single fp16) in tiled fragment order.
// LDS 16 KB -> up to 9 blocks/CU; 4 global_load_lds + 8 ds_read_b128 +
// 16 MFMA per wave per k-iter.
// WRITE_C: store fp32 C.  WRITE_XS: store xs = fp16(out * norm_out[row]).
// Dual-output on columns >= 512 (block-uniform): Cb / bias_b / RELU_B.
template <bool RELU_A, bool RELU_B, bool WRITE_C, bool WRITE_XS>
__global__ __launch_bounds__(256) void mfma_gemm(
        const _Float16* __restrict__ A_hi, const _Float16* __restrict__ A_lo,
        const _Float16* __restrict__ Bt,
        const float* __restrict__ bias_a, const float* __restrict__ bias_b,
        const float* __restrict__ norm_out,
        float* __restrict__ Ca, float* __restrict__ Cb,
        _Float16* __restrict__ xs) {
    __shared__ __align__(16) _Float16 lsA[2][64 * 32];    // [hi/lo], 4 strips: 8 KB
    __shared__ __align__(16) _Float16 lsB[128 * 32];      // 8 strips: 8 KB
    int tid = threadIdx.x;
    int w = tid >> 6, lane = tid & 63;
    int col0 = blockIdx.x * 128;
    int row0 = blockIdx.y * 64;
    int wm = w & 1, wn = w >> 1;
    int lr = lane & 15, lq = lane >> 4;

    size_t aoff = (size_t)((row0 >> 4) + w) * 8192 + lane * 8;
    size_t boff = (size_t)((col0 >> 4) + 2 * w) * 8192 + lane * 8;
    _Float16* dAh = &lsA[0][(w * 64 + lane) * 8];
    _Float16* dAl = &lsA[1][(w * 64 + lane) * 8];
    _Float16* dB0 = &lsB[((2 * w) * 64 + lane) * 8];
    _Float16* dB1 = &lsB[((2 * w + 1) * 64 + lane) * 8];

    f32x4 acc[2][4] = {};

    for (int kb = 0; kb < 16; kb++) {
        size_t ko = (size_t)kb * 512;
        load_lds16(A_hi + aoff + ko, dAh);
        load_lds16(A_lo + aoff + ko, dAl);
        load_lds16(Bt + boff + ko, dB0);
        load_lds16(Bt + boff + 8192 + ko, dB1);
        __syncthreads();

        half8 ah[2], al[2], b[4];
#pragma unroll
        for (int i = 0; i < 2; i++) {
            ah[i] = *(const half8*)&lsA[0][((wm * 2 + i) * 64 + lane) * 8];
            al[i] = *(const half8*)&lsA[1][((wm * 2 + i) * 64 + lane) * 8];
        }
#pragma unroll
        for (int j = 0; j < 4; j++)
            b[j] = *(const half8*)&lsB[((wn * 4 + j) * 64 + lane) * 8];
#pragma unroll
        for (int i = 0; i < 2; i++)
#pragma unroll
            for (int j = 0; j < 4; j++) {
                acc[i][j] = __builtin_amdgcn_mfma_f32_16x16x32_f16(ah[i], b[j], acc[i][j], 0, 0, 0);
                acc[i][j] = __builtin_amdgcn_mfma_f32_16x16x32_f16(al[i], b[j], acc[i][j], 0, 0, 0);
            }
        __syncthreads();
    }

    bool sec = (col0 >= 512);                 // block-uniform
    const float* bias = sec ? bias_b : bias_a;
    float* C = sec ? Cb : Ca;
    int cb0 = sec ? col0 - 512 : col0;
    const bool relu = sec ? RELU_B : RELU_A;

#pragma unroll
    for (int i = 0; i < 2; i++)
#pragma unroll
        for (int j = 0; j < 4; j++) {
            int col = cb0 + wn * 64 + j * 16 + lr;
            float bv = bias[col];
#pragma unroll
            for (int r = 0; r < 4; r++) {
                int row = row0 + wm * 32 + i * 16 + lq * 4 + r;
                if (row < N_NODES) {
                    float v = acc[i][j][r] + bv;
                    if (relu) v = fmaxf(v, 0.f);
                    if (WRITE_C) C[(size_t)row * 512 + col] = v;
                    if (WRITE_XS)
                        xs[(size_t)row * 512 + col] = (_Float16)(v * norm_out[row]);
                }
            }
        }
}

extern "C" void kernel_launch(void* const* d_in, const int* in_sizes, int n_in,
                              void* d_out, int out_size, void* d_ws, size_t ws_size,
                              hipStream_t stream) {
    const float* x  = (const float*)d_in[0];
    const float* W1 = (const float*)d_in[1];
    const float* b1 = (const float*)d_in[2];
    const float* W2 = (const float*)d_in[3];
    const float* b2 = (const float*)d_in[4];
    const float* W3 = (const float*)d_in[5];
    const float* b3 = (const float*)d_in[6];
    const int* src  = (const int*)d_in[7];
    const int* dst  = (const int*)d_in[8];
    float* out = (float*)d_out;

    // workspace layout
    int* wsi = (int*)d_ws;
    int* deg_out  = wsi;                       // 10000
    int* deg_in   = wsi + 10000;               // 10000
    float* norm_out = (float*)(wsi + 20000);   // 10000
    float* norm_in  = (float*)(wsi + 30000);   // 10000
    int* row_ptr  = wsi + 40000;               // 10001 (pad to 10016)
    int* cursor   = wsi + 50016;               // 10000
    int* edge_src = wsi + 60016;               // 160000  -> ends at int 220016
    _Float16* wt   = (_Float16*)(wsi + 220016);        // 3 * 262144 halves (tiled)
    _Float16* a_hi = wt + 786432;                      // M_PAD * 512 (tiled)
    _Float16* a_lo = a_hi + (size_t)M_PAD * 512;
    _Float16* xs   = a_lo + (size_t)M_PAD * 512;       // N_NODES * 512
    // total ~32.5 MB

    // d_out layout: [h4 | h3 | h2]
    float* h4 = out;
    float* h3 = out + 5120000;
    float* h2 = out + 10240000;

    hipMemsetAsync(d_ws, 0, 20000 * sizeof(int), stream);  // deg_out + deg_in

    deg_kernel<<<(N_EDGES + 255) / 256, 256, 0, stream>>>(src, dst, deg_out, deg_in);
    norm_kernel<<<(N_NODES + 255) / 256, 256, 0, stream>>>(deg_out, deg_in, norm_out, norm_in);
    scan_kernel<<<1, 256, 0, stream>>>(deg_in, row_ptr, cursor);
    fill_kernel<<<(N_EDGES + 255) / 256, 256, 0, stream>>>(src, dst, cursor, edge_src);
    wsplit_kernel<<<dim3(128, 3), 256, 0, stream>>>(W1, W2, W3, wt);
    prescale_kernel<<<(N_NODES * 64 + 255) / 256, 256, 0, stream>>>(x, norm_out, xs);

    _Float16* wt1 = wt;
    _Float16* wt2 = wt + 262144;   // W2^T | W3^T contiguous for the fused GEMM

    dim3 g1(4, M_PAD / 64);   // N = 512   (col-blocks fast -> A-panel reuse)
    dim3 g2(8, M_PAD / 64);   // N = 1024  (fused h3|h4)

    // layer 1: h1 never materialized in fp32 — GEMM writes xs only
    agg_kernel<<<M_PAD, 64, 0, stream>>>(xs, edge_src, row_ptr, norm_in, a_hi, a_lo);
    mfma_gemm<true, true, false, true><<<g1, 256, 0, stream>>>(
        a_hi, a_lo, wt1, b1, b1, norm_out, h2, h2, xs);
    // layer 2: h2 is an output AND feeds agg3 via xs
    agg_kernel<<<M_PAD, 64, 0, stream>>>(xs, edge_src, row_ptr, norm_in, a_hi, a_lo);
    mfma_gemm<true, true, true, true><<<g1, 256, 0, stream>>>(
        a_hi, a_lo, wt2, b2, b2, norm_out, h2, h2, xs);
    // layers 3 & 4 share the aggregation of h2; one fused N=1024 GEMM
    agg_kernel<<<M_PAD, 64, 0, stream>>>(xs, edge_src, row_ptr, norm_in, a_hi, a_lo);
    mfma_gemm<true, false, true, false><<<g2, 256, 0, stream>>>(
        a_hi, a_lo, wt2, b2, b3, norm_out, h3, h4, xs);
}

// Round 7
// 289.879 us; speedup vs baseline: 1.5136x; 1.1627x over previous
//
#include <hip/hip_runtime.h>

#define N_NODES 10000
#define N_EDGES 160000
#define FEAT 512
#define M_PAD 10048        // 157 * 64
#define QSTRIDE 1286144    // quarter stride in halves: N_PAD(10048)*128 = 1286144

typedef unsigned int uint32;

typedef __attribute__((ext_vector_type(8))) _Float16 half8;     // 16 B = MFMA A/B frag
typedef __attribute__((ext_vector_type(4))) float f32x4;        // MFMA C/D

// ---- tiled ("fragment order") fp16 layout for a R x 512 matrix ----
// strip s = row>>4 (16 rows), k-block kb = k>>5 (32 k). Each (s,kb) is a 1 KB
// tile; half-elem offset = s*8192 + kb*512 + (kq*16 + (row&15))*8 + (k&7),
// kq = (k>>3)&3.  A wave staging tile (s,kb) reads global base+lane*16B
// (contiguous 1 KB) and global_load_lds drops lane's 16B at lds_base+lane*16B,
// which is exactly the MFMA A/B fragment order for 16x16x32.
//
// ---- quarter-major xs layout (gather source) ----
// xs[q*QSTRIDE + node*128 + f], q = feat>>7, f = feat&127. One quarter is
// 2.56 MB < 4 MiB per-XCD L2 -> agg pass over one quarter is L2-resident.

__device__ __forceinline__ void load_lds16(const void* g, void* l) {
    __builtin_amdgcn_global_load_lds(
        (const __attribute__((address_space(1))) void*)g,
        (__attribute__((address_space(3))) void*)l, 16, 0, 0);
}

// ---------------- degree count ----------------
__global__ void deg_kernel(const int* __restrict__ src, const int* __restrict__ dst,
                           int* __restrict__ deg_out, int* __restrict__ deg_in) {
    int e = blockIdx.x * blockDim.x + threadIdx.x;
    if (e < N_EDGES) {
        atomicAdd(&deg_out[src[e]], 1);
        atomicAdd(&deg_in[dst[e]], 1);
    }
}

// ---------------- norms ----------------
__global__ void norm_kernel(const int* __restrict__ deg_out, const int* __restrict__ deg_in,
                            float* __restrict__ norm_out, float* __restrict__ norm_in) {
    int i = blockIdx.x * blockDim.x + threadIdx.x;
    if (i < N_NODES) {
        int dob = deg_out[i], dib = deg_in[i];
        norm_out[i] = dob > 0 ? rsqrtf((float)dob) : 0.f;
        norm_in[i]  = dib > 0 ? rsqrtf((float)dib) : 0.f;
    }
}

// ---------------- exclusive scan of in-degrees ----------------
__global__ void scan_kernel(const int* __restrict__ deg_in,
                            int* __restrict__ row_ptr, int* __restrict__ cursor) {
    __shared__ int sums[256];
    const int CHUNK = 40;
    int t = threadIdx.x;
    int start = t * CHUNK;
    int s = 0;
    for (int j = 0; j < CHUNK; j++) {
        int i = start + j;
        if (i < N_NODES) s += deg_in[i];
    }
    sums[t] = s;
    __syncthreads();
    for (int off = 1; off < 256; off <<= 1) {
        int v = (t >= off) ? sums[t - off] : 0;
        __syncthreads();
        sums[t] += v;
        __syncthreads();
    }
    int run = (t > 0) ? sums[t - 1] : 0;
    for (int j = 0; j < CHUNK; j++) {
        int i = start + j;
        if (i < N_NODES) {
            row_ptr[i] = run;
            cursor[i] = run;
            run += deg_in[i];
        }
    }
    if (t == 0) row_ptr[N_NODES] = sums[255];
}

// ---------------- CSR fill ----------------
__global__ void fill_kernel(const int* __restrict__ src, const int* __restrict__ dst,
                            int* __restrict__ cursor, int* __restrict__ edge_src) {
    int e = blockIdx.x * blockDim.x + threadIdx.x;
    if (e < N_EDGES) {
        int d = dst[e];
        int pos = atomicAdd(&cursor[d], 1);
        edge_src[pos] = src[e];
    }
}

// ---------------- prescale: xs = fp16(x * norm_out), quarter-major ----------------
__global__ __launch_bounds__(256) void prescale_kernel(const float* __restrict__ x,
        const float* __restrict__ norm_out, _Float16* __restrict__ xs) {
    int idx = blockIdx.x * 256 + threadIdx.x;     // one per 8 floats
    if (idx >= N_NODES * 64) return;
    int node = idx >> 6, f8 = idx & 63;
    float w = norm_out[node];
    const float4* p = (const float4*)&x[(size_t)node * 512 + f8 * 8];
    float4 a = p[0], b = p[1];
    half8 h;
    h[0] = (_Float16)(a.x * w); h[1] = (_Float16)(a.y * w);
    h[2] = (_Float16)(a.z * w); h[3] = (_Float16)(a.w * w);
    h[4] = (_Float16)(b.x * w); h[5] = (_Float16)(b.y * w);
    h[6] = (_Float16)(b.z * w); h[7] = (_Float16)(b.w * w);
    int q = f8 >> 4, fl8 = f8 & 15;
    *(half8*)&xs[(size_t)q * QSTRIDE + (size_t)node * 128 + fl8 * 8] = h;
}

// ---------------- aggregation v4: quarter-resident gather ----------------
// grid (M_PAD, 4): blockIdx.y = quarter (x-fastest dispatch keeps one quarter's
// 2.56 MB hot in each XCD L2). One wave per (dst, quarter): 16 lanes per edge
// (256 B row-quarter), 4 edges in flight, 2x unrolled; __shfl_xor reduce.
__global__ __launch_bounds__(64) void agg_kernel(const _Float16* __restrict__ xs,
        const int* __restrict__ edge_src, const int* __restrict__ row_ptr,
        const float* __restrict__ norm_in, _Float16* __restrict__ a_t) {
    int lane = threadIdx.x;
    int d = blockIdx.x, q = blockIdx.y;
    int fl = lane & 15, g = lane >> 4;
    float acc[8] = {};
    if (d < N_NODES) {
        int beg = row_ptr[d], end = row_ptr[d + 1];
        const _Float16* xq = xs + (size_t)q * QSTRIDE + fl * 8;
        int e = beg + g;
        for (; e + 4 < end; e += 8) {
            int s0 = edge_src[e], s1 = edge_src[e + 4];
            half8 v0 = *(const half8*)&xq[(size_t)s0 * 128];
            half8 v1 = *(const half8*)&xq[(size_t)s1 * 128];
#pragma unroll
            for (int i = 0; i < 8; i++) acc[i] += (float)v0[i] + (float)v1[i];
        }
        for (; e < end; e += 4) {
            int s = edge_src[e];
            half8 v = *(const half8*)&xq[(size_t)s * 128];
#pragma unroll
            for (int i = 0; i < 8; i++) acc[i] += (float)v[i];
        }
        // reduce the 4 edge-groups (lanes xor 16, 32)
#pragma unroll
        for (int i = 0; i < 8; i++) {
            acc[i] += __shfl_xor(acc[i], 16);
            acc[i] += __shfl_xor(acc[i], 32);
        }
        float ni = norm_in[d];
#pragma unroll
        for (int i = 0; i < 8; i++) acc[i] *= ni;
    }
    if (g == 0) {
        half8 h8;
#pragma unroll
        for (int i = 0; i < 8; i++) h8[i] = (_Float16)acc[i];
        // tiled A layout: k0 = q*128 + fl*8 -> kb = q*4 + (fl>>2), kq = fl&3
        size_t o = (size_t)(d >> 4) * 8192 + (size_t)(q * 4 + (fl >> 2)) * 512
                 + (size_t)((fl & 3) * 16 + (d & 15)) * 8;
        *(half8*)&a_t[o] = h8;
    }
}

// ---------------- W (KxN fp32) -> tiled W^T fp16 ----------------
__global__ __launch_bounds__(256) void wsplit_kernel(const float* __restrict__ W1,
        const float* __restrict__ W2, const float* __restrict__ W3,
        _Float16* __restrict__ wt) {
    const float* W = blockIdx.y == 0 ? W1 : (blockIdx.y == 1 ? W2 : W3);
    size_t mbase = (size_t)blockIdx.y * 262144;
    int chunk = blockIdx.x * 256 + threadIdx.x;    // 0..32767
    int i = chunk & 63;
    int kb = (chunk >> 6) & 15;
    int s = chunk >> 10;
    int n = s * 16 + (i & 15);
    int k0 = kb * 32 + (i >> 4) * 8;
    half8 h8;
#pragma unroll
    for (int j = 0; j < 8; j++)
        h8[j] = (_Float16)W[(size_t)(k0 + j) * 512 + n];
    *(half8*)&wt[mbase + (size_t)chunk * 8] = h8;
}

// ---------------- 1-term fp16 MFMA GEMM, tiled inputs ----------------
// C = A(M_PAD x 512) @ W(512 x N) + bias.  BM=64, BN=128, BK=32; 4 waves,
// wave tile 32x64 (2x4 16x16x32 f16 MFMA). LDS 12 KB. Per wave per k-iter:
// 3 global_load_lds(16B) + 6 ds_read_b128 + 8 MFMA.
// WRITE_C: store fp32 C.  WRITE_XS: store xs = fp16(out*norm_out), quarter-major.
// Dual-output on columns >= 512 (block-uniform): Cb / bias_b / RELU_B.
template <bool RELU_A, bool RELU_B, bool WRITE_C, bool WRITE_XS>
__global__ __launch_bounds__(256) void mfma_gemm(
        const _Float16* __restrict__ A_t, const _Float16* __restrict__ Bt,
        const float* __restrict__ bias_a, const float* __restrict__ bias_b,
        const float* __restrict__ norm_out,
        float* __restrict__ Ca, float* __restrict__ Cb,
        _Float16* __restrict__ xs) {
    __shared__ __align__(16) _Float16 lsA[64 * 32];       // 4 strips: 4 KB
    __shared__ __align__(16) _Float16 lsB[128 * 32];      // 8 strips: 8 KB
    int tid = threadIdx.x;
    int w = tid >> 6, lane = tid & 63;
    int col0 = blockIdx.x * 128;
    int row0 = blockIdx.y * 64;
    int wm = w & 1, wn = w >> 1;
    int lr = lane & 15, lq = lane >> 4;

    size_t aoff = (size_t)((row0 >> 4) + w) * 8192 + lane * 8;
    size_t boff = (size_t)((col0 >> 4) + 2 * w) * 8192 + lane * 8;
    _Float16* dA  = &lsA[(w * 64 + lane) * 8];
    _Float16* dB0 = &lsB[((2 * w) * 64 + lane) * 8];
    _Float16* dB1 = &lsB[((2 * w + 1) * 64 + lane) * 8];

    f32x4 acc[2][4] = {};

    for (int kb = 0; kb < 16; kb++) {
        size_t ko = (size_t)kb * 512;
        load_lds16(A_t + aoff + ko, dA);
        load_lds16(Bt + boff + ko, dB0);
        load_lds16(Bt + boff + 8192 + ko, dB1);
        __syncthreads();

        half8 a[2], b[4];
#pragma unroll
        for (int i = 0; i < 2; i++)
            a[i] = *(const half8*)&lsA[((wm * 2 + i) * 64 + lane) * 8];
#pragma unroll
        for (int j = 0; j < 4; j++)
            b[j] = *(const half8*)&lsB[((wn * 4 + j) * 64 + lane) * 8];
#pragma unroll
        for (int i = 0; i < 2; i++)
#pragma unroll
            for (int j = 0; j < 4; j++)
                acc[i][j] = __builtin_amdgcn_mfma_f32_16x16x32_f16(a[i], b[j], acc[i][j], 0, 0, 0);
        __syncthreads();
    }

    bool sec = (col0 >= 512);                 // block-uniform
    const float* bias = sec ? bias_b : bias_a;
    float* C = sec ? Cb : Ca;
    int cb0 = sec ? col0 - 512 : col0;
    const bool relu = sec ? RELU_B : RELU_A;

#pragma unroll
    for (int i = 0; i < 2; i++)
#pragma unroll
        for (int j = 0; j < 4; j++) {
            int col = cb0 + wn * 64 + j * 16 + lr;
            float bv = bias[col];
#pragma unroll
            for (int r = 0; r < 4; r++) {
                int row = row0 + wm * 32 + i * 16 + lq * 4 + r;
                if (row < N_NODES) {
                    float v = acc[i][j][r] + bv;
                    if (relu) v = fmaxf(v, 0.f);
                    if (WRITE_C) C[(size_t)row * 512 + col] = v;
                    if (WRITE_XS) {
                        int q = col >> 7, f = col & 127;
                        xs[(size_t)q * QSTRIDE + (size_t)row * 128 + f] =
                            (_Float16)(v * norm_out[row]);
                    }
                }
            }
        }
}

extern "C" void kernel_launch(void* const* d_in, const int* in_sizes, int n_in,
                              void* d_out, int out_size, void* d_ws, size_t ws_size,
                              hipStream_t stream) {
    const float* x  = (const float*)d_in[0];
    const float* W1 = (const float*)d_in[1];
    const float* b1 = (const float*)d_in[2];
    const float* W2 = (const float*)d_in[3];
    const float* b2 = (const float*)d_in[4];
    const float* W3 = (const float*)d_in[5];
    const float* b3 = (const float*)d_in[6];
    const int* src  = (const int*)d_in[7];
    const int* dst  = (const int*)d_in[8];
    float* out = (float*)d_out;

    // workspace layout
    int* wsi = (int*)d_ws;
    int* deg_out  = wsi;                       // 10000
    int* deg_in   = wsi + 10000;               // 10000
    float* norm_out = (float*)(wsi + 20000);   // 10000
    float* norm_in  = (float*)(wsi + 30000);   // 10000
    int* row_ptr  = wsi + 40000;               // 10001 (pad to 10016)
    int* cursor   = wsi + 50016;               // 10000
    int* edge_src = wsi + 60016;               // 160000  -> ends at int 220016
    _Float16* wt  = (_Float16*)(wsi + 220016);         // 3 * 262144 halves (tiled)
    _Float16* a_t = wt + 786432;                       // M_PAD * 512 (tiled)
    _Float16* xs  = a_t + (size_t)M_PAD * 512;         // 4 * QSTRIDE (quarter-major)
    // total ~22.7 MB

    // d_out layout: [h4 | h3 | h2]
    float* h4 = out;
    float* h3 = out + 5120000;
    float* h2 = out + 10240000;

    hipMemsetAsync(d_ws, 0, 20000 * sizeof(int), stream);  // deg_out + deg_in

    deg_kernel<<<(N_EDGES + 255) / 256, 256, 0, stream>>>(src, dst, deg_out, deg_in);
    norm_kernel<<<(N_NODES + 255) / 256, 256, 0, stream>>>(deg_out, deg_in, norm_out, norm_in);
    scan_kernel<<<1, 256, 0, stream>>>(deg_in, row_ptr, cursor);
    fill_kernel<<<(N_EDGES + 255) / 256, 256, 0, stream>>>(src, dst, cursor, edge_src);
    wsplit_kernel<<<dim3(128, 3), 256, 0, stream>>>(W1, W2, W3, wt);
    prescale_kernel<<<(N_NODES * 64 + 255) / 256, 256, 0, stream>>>(x, norm_out, xs);

    _Float16* wt1 = wt;
    _Float16* wt2 = wt + 262144;   // W2^T | W3^T contiguous for the fused GEMM

    dim3 ga(M_PAD, 4);        // agg: quarter-major
    dim3 g1(4, M_PAD / 64);   // N = 512   (col-blocks fast -> A-panel reuse)
    dim3 g2(8, M_PAD / 64);   // N = 1024  (fused h3|h4)

    // layer 1: h1 never materialized in fp32 — GEMM writes xs only
    agg_kernel<<<ga, 64, 0, stream>>>(xs, edge_src, row_ptr, norm_in, a_t);
    mfma_gemm<true, true, false, true><<<g1, 256, 0, stream>>>(
        a_t, wt1, b1, b1, norm_out, h2, h2, xs);
    // layer 2: h2 is an output AND feeds agg3 via xs
    agg_kernel<<<ga, 64, 0, stream>>>(xs, edge_src, row_ptr, norm_in, a_t);
    mfma_gemm<true, true, true, true><<<g1, 256, 0, stream>>>(
        a_t, wt2, b2, b2, norm_out, h2, h2, xs);
    // layers 3 & 4 share the aggregation of h2; one fused N=1024 GEMM
    agg_kernel<<<ga, 64, 0, stream>>>(xs, edge_src, row_ptr, norm_in, a_t);
    mfma_gemm<true, false, true, false><<<g2, 256, 0, stream>>>(
        a_t, wt2, b2, b3, norm_out, h3, h4, xs);
}